// Round 3
// baseline (169.833 us; speedup 1.0000x reference)
//
#include <hip/hip_runtime.h>

// BCELoss(reduce=False) + "already-correct -> 0" masking, N fp32 elements.
//   q = (y==1) ? p : 1-p;  loss = (q > 0.5) ? 0 : -max(ln q, -100)
// R1 analysis: VALUBusy 6.5%, HBM 28% -> latency-bound (1 float4/thread,
// one HBM round trip per wave life). R2: K=8 float4 pairs per thread, all
// loads issued independently (256 B/lane in flight), 8x fewer workgroups.

#define K 8   // float4 iterations per thread

__device__ __forceinline__ float bce1(float p, float y) {
    float q = (y == 1.0f) ? p : (1.0f - p);
    float lg = __builtin_amdgcn_logf(q) * 0.6931471805599453f;  // v_log_f32 -> ln
    float ll = fmaxf(lg, -100.0f);   // torch clamp (inert for q >= 1e-4)
    return (q > 0.5f) ? 0.0f : -ll;
}

__device__ __forceinline__ float4 bce4(float4 p, float4 y) {
    float4 o;
    o.x = bce1(p.x, y.x);
    o.y = bce1(p.y, y.y);
    o.z = bce1(p.z, y.z);
    o.w = bce1(p.w, y.w);
    return o;
}

__global__ void __launch_bounds__(256)
bce_loss_kernel(const float4* __restrict__ p4,
                const float4* __restrict__ y4,
                float4* __restrict__ o4,
                int n4,
                const float* __restrict__ p_s,
                const float* __restrict__ y_s,
                float* __restrict__ o_s,
                int n) {
    long base = (long)blockIdx.x * (256 * K) + threadIdx.x;

    if (base + 256 * (K - 1) < n4) {
        // fast path: all K in range. Issue all loads first (independent ->
        // compiler keeps 2K loads in flight before the first waitcnt).
        float4 p[K], y[K];
        #pragma unroll
        for (int k = 0; k < K; ++k) p[k] = p4[base + (long)k * 256];
        #pragma unroll
        for (int k = 0; k < K; ++k) y[k] = y4[base + (long)k * 256];
        #pragma unroll
        for (int k = 0; k < K; ++k) o4[base + (long)k * 256] = bce4(p[k], y[k]);
    } else {
        // edge block: per-iteration guard
        #pragma unroll
        for (int k = 0; k < K; ++k) {
            long i = base + (long)k * 256;
            if (i < n4) o4[i] = bce4(p4[i], y4[i]);
        }
    }

    // scalar tail (n % 4) — empty for N = 2^24
    if (base == 0) {
        for (int j = n4 * 4; j < n; ++j) {
            o_s[j] = bce1(p_s[j], y_s[j]);
        }
    }
}

extern "C" void kernel_launch(void* const* d_in, const int* in_sizes, int n_in,
                              void* d_out, int out_size, void* d_ws, size_t ws_size,
                              hipStream_t stream) {
    const float* y_pred   = (const float*)d_in[0];
    const float* y_actual = (const float*)d_in[1];
    float* out = (float*)d_out;
    int n  = in_sizes[0];
    int n4 = n >> 2;

    const int block = 256;
    const int per_block = block * K;                 // float4s per block
    int grid = (n4 + per_block - 1) / per_block;     // 2048 for N=2^24
    bce_loss_kernel<<<grid, block, 0, stream>>>(
        (const float4*)y_pred, (const float4*)y_actual, (float4*)out, n4,
        y_pred, y_actual, out, n);
}

// Round 5
// 157.811 us; speedup vs baseline: 1.0762x; 1.0762x over previous
//
#include <hip/hip_runtime.h>

// BCELoss(reduce=False) + "already-correct -> 0" masking, N fp32 elements.
//   q = (y==1) ? p : 1-p;  loss = (q > 0.5) ? 0 : -max(ln q, -100)
// R0/R1/R2 all pinned at ~60-65 us (~2.1 TB/s HBM) regardless of VALU load
// or in-flight bytes -> memory-system-bound, not pipe-bound. R4 = R3 retry:
// nontemporal (nt) loads+stores via native clang vector type (the builtin
// rejects HIP_vector_type structs) so the streaming output doesn't
// allocate/RFO in L2/L3 and input lines are evict-first (zero reuse anyway).

typedef float vfloat4 __attribute__((ext_vector_type(4)));

__device__ __forceinline__ float bce1(float p, float y) {
    float q = (y == 1.0f) ? p : (1.0f - p);
    float lg = __builtin_amdgcn_logf(q) * 0.6931471805599453f;  // v_log_f32 -> ln
    float ll = fmaxf(lg, -100.0f);   // torch clamp (inert for q >= 1e-4)
    return (q > 0.5f) ? 0.0f : -ll;
}

__global__ void __launch_bounds__(256)
bce_loss_kernel(const vfloat4* __restrict__ p4,
                const vfloat4* __restrict__ y4,
                vfloat4* __restrict__ o4,
                int n4,
                const float* __restrict__ p_s,
                const float* __restrict__ y_s,
                float* __restrict__ o_s,
                int n) {
    int i = blockIdx.x * blockDim.x + threadIdx.x;
    if (i < n4) {
        vfloat4 p = __builtin_nontemporal_load(&p4[i]);
        vfloat4 y = __builtin_nontemporal_load(&y4[i]);
        vfloat4 o;
        o.x = bce1(p.x, y.x);
        o.y = bce1(p.y, y.y);
        o.z = bce1(p.z, y.z);
        o.w = bce1(p.w, y.w);
        __builtin_nontemporal_store(o, &o4[i]);
    }
    // scalar tail (n % 4) — empty for N = 2^24
    if (i == 0) {
        for (int j = n4 * 4; j < n; ++j) {
            float pj = __builtin_nontemporal_load(&p_s[j]);
            float yj = __builtin_nontemporal_load(&y_s[j]);
            __builtin_nontemporal_store(bce1(pj, yj), &o_s[j]);
        }
    }
}

extern "C" void kernel_launch(void* const* d_in, const int* in_sizes, int n_in,
                              void* d_out, int out_size, void* d_ws, size_t ws_size,
                              hipStream_t stream) {
    const float* y_pred   = (const float*)d_in[0];
    const float* y_actual = (const float*)d_in[1];
    float* out = (float*)d_out;
    int n  = in_sizes[0];
    int n4 = n >> 2;

    const int block = 256;
    int grid = (n4 + block - 1) / block;   // 16384 blocks for N=2^24
    bce_loss_kernel<<<grid, block, 0, stream>>>(
        (const vfloat4*)y_pred, (const vfloat4*)y_actual, (vfloat4*)out, n4,
        y_pred, y_actual, out, n);
}

// Round 6
// 156.917 us; speedup vs baseline: 1.0823x; 1.0057x over previous
//
#include <hip/hip_runtime.h>

// BCELoss(reduce=False) + "already-correct -> 0" masking, N fp32 elements.
//   q = (y==1) ? p : 1-p;  loss = (q > 0.5) ? 0 : -max(ln q, -100)
// R4: nontemporal loads/stores broke the ~2.1 TB/s L2-write-allocate wall
// (kernel now <40 us, off the top-5). R5: same nt regime + K=4 float4 per
// thread (stride-blockDim, coalesced) for 128 B/lane in flight and 4x less
// wave churn -> push toward the 192 MiB / 6.3 TB/s ~ 30 us floor.

typedef float vfloat4 __attribute__((ext_vector_type(4)));

#define K 4   // float4s per thread

__device__ __forceinline__ float bce1(float p, float y) {
    float q = (y == 1.0f) ? p : (1.0f - p);
    float lg = __builtin_amdgcn_logf(q) * 0.6931471805599453f;  // v_log_f32 -> ln
    float ll = fmaxf(lg, -100.0f);   // torch clamp (inert for q >= 1e-4)
    return (q > 0.5f) ? 0.0f : -ll;
}

__device__ __forceinline__ vfloat4 bce4(vfloat4 p, vfloat4 y) {
    vfloat4 o;
    o.x = bce1(p.x, y.x);
    o.y = bce1(p.y, y.y);
    o.z = bce1(p.z, y.z);
    o.w = bce1(p.w, y.w);
    return o;
}

__global__ void __launch_bounds__(256)
bce_loss_kernel(const vfloat4* __restrict__ p4,
                const vfloat4* __restrict__ y4,
                vfloat4* __restrict__ o4,
                int n4,
                const float* __restrict__ p_s,
                const float* __restrict__ y_s,
                float* __restrict__ o_s,
                int n) {
    int base = blockIdx.x * (256 * K) + threadIdx.x;

    if (base + 256 * (K - 1) < n4) {
        // fast path: all K in range; issue all 2K nt loads before first use
        vfloat4 p[K], y[K];
        #pragma unroll
        for (int k = 0; k < K; ++k) p[k] = __builtin_nontemporal_load(&p4[base + k * 256]);
        #pragma unroll
        for (int k = 0; k < K; ++k) y[k] = __builtin_nontemporal_load(&y4[base + k * 256]);
        #pragma unroll
        for (int k = 0; k < K; ++k)
            __builtin_nontemporal_store(bce4(p[k], y[k]), &o4[base + k * 256]);
    } else {
        #pragma unroll
        for (int k = 0; k < K; ++k) {
            int i = base + k * 256;
            if (i < n4) {
                vfloat4 p = __builtin_nontemporal_load(&p4[i]);
                vfloat4 y = __builtin_nontemporal_load(&y4[i]);
                __builtin_nontemporal_store(bce4(p, y), &o4[i]);
            }
        }
    }

    // scalar tail (n % 4) — empty for N = 2^24
    if (base == 0) {
        for (int j = n4 * 4; j < n; ++j) {
            float pj = __builtin_nontemporal_load(&p_s[j]);
            float yj = __builtin_nontemporal_load(&y_s[j]);
            __builtin_nontemporal_store(bce1(pj, yj), &o_s[j]);
        }
    }
}

extern "C" void kernel_launch(void* const* d_in, const int* in_sizes, int n_in,
                              void* d_out, int out_size, void* d_ws, size_t ws_size,
                              hipStream_t stream) {
    const float* y_pred   = (const float*)d_in[0];
    const float* y_actual = (const float*)d_in[1];
    float* out = (float*)d_out;
    int n  = in_sizes[0];
    int n4 = n >> 2;

    const int block = 256;
    const int per_block = block * K;               // float4s per block
    int grid = (n4 + per_block - 1) / per_block;   // 4096 for N=2^24
    bce_loss_kernel<<<grid, block, 0, stream>>>(
        (const vfloat4*)y_pred, (const vfloat4*)y_actual, (vfloat4*)out, n4,
        y_pred, y_actual, out, n);
}